// Round 11
// baseline (1708.098 us; speedup 1.0000x reference)
//
#include <hip/hip_runtime.h>
#include <hip/hip_fp16.h>
#include <math.h>

#define N_NODES 50000
#define N_EDGES 800000
#define D 128
#define T_TYPES 8
#define TPAD 136   // LDS row stride (ushorts): 68 dwords -> row shifts 4 banks
#define NBLK_SCAN 196   // ceil(50000/256)
#define TILES 1563      // ceil(50000/32)
#define HT_PLANE 6400000   // ushorts per type plane (50000*128)

typedef short short8 __attribute__((ext_vector_type(8)));
typedef unsigned short ushort4v __attribute__((ext_vector_type(4)));
typedef float float4v __attribute__((ext_vector_type(4)));
typedef unsigned short ushort_t;

static __device__ __forceinline__ unsigned short f2bf(float f) {
    unsigned u = __float_as_uint(f);
    u += 0x7fff + ((u >> 16) & 1);   // round-to-nearest-even
    return (unsigned short)(u >> 16);
}
static __device__ __forceinline__ float bf2f(unsigned short b) {
    return __uint_as_float((unsigned)b << 16);
}
// exact two-term split: x ~= hi + lo, error <= 2^-18 |x|
static __device__ __forceinline__ void splitbf(float x, unsigned short& hi, unsigned short& lo) {
    unsigned short h_ = f2bf(x);
    hi = h_;
    lo = f2bf(x - bf2f(h_));
}

// ---------------------------------------------------------------------------
// h fp32 is NOT written here: gru_direct(it==4) writes every node's row.
__global__ void embed_gather(const int* __restrict__ x, const float* __restrict__ emb,
                             ushort_t* __restrict__ hhi, ushort_t* __restrict__ hlo) {
    int n = blockIdx.x;
    int d = threadIdx.x;
    float v = emb[(size_t)x[n] * D + d];
    unsigned short a, b;
    splitbf(v, a, b);
    hhi[(size_t)n * D + d] = a;
    hlo[(size_t)n * D + d] = b;
}

// WrelT[t][f][d] = Wrel[t][d][f], split hi/lo bf16
__global__ void convert_wrelT(const float* __restrict__ Wrel,
                              ushort_t* __restrict__ hi, ushort_t* __restrict__ lo) {
    int idx = blockIdx.x * 256 + threadIdx.x; // 0..131071
    int t = idx >> 14;
    int rem = idx & 16383;
    int f = rem >> 7;
    int d = rem & 127;
    unsigned short a, b;
    splitbf(Wrel[((size_t)t << 14) + (d << 7) + f], a, b);
    hi[idx] = a;
    lo[idx] = b;
}

// GRU weights keep [3D][D] layout (already B^T form), split hi/lo
__global__ void convert_w(const float* __restrict__ in,
                          ushort_t* __restrict__ hi, ushort_t* __restrict__ lo, int n) {
    int idx = blockIdx.x * 256 + threadIdx.x;
    if (idx < n) {
        unsigned short a, b;
        splitbf(in[idx], a, b);
        hi[idx] = a;
        lo[idx] = b;
    }
}

// ---------------------------------------------------------------------------
// CSR build over dst
__global__ void count_deg(const int* __restrict__ ei, int* __restrict__ deg) {
    int e = blockIdx.x * 256 + threadIdx.x;
    if (e >= N_EDGES) return;
    atomicAdd(&deg[ei[N_EDGES + e]], 1);
}

__global__ __launch_bounds__(256) void scan_blocks(const int* __restrict__ deg,
                                                   int* __restrict__ bsums) {
    __shared__ int red[4];
    int idx = blockIdx.x * 256 + threadIdx.x;
    int v = (idx < N_NODES) ? deg[idx] : 0;
#pragma unroll
    for (int o = 32; o > 0; o >>= 1) v += __shfl_down(v, o);
    if ((threadIdx.x & 63) == 0) red[threadIdx.x >> 6] = v;
    __syncthreads();
    if (threadIdx.x == 0) bsums[blockIdx.x] = red[0] + red[1] + red[2] + red[3];
}

__global__ __launch_bounds__(256) void scan_tops(int* __restrict__ bsums) {
    __shared__ int s[256];
    int tid = threadIdx.x;
    int v = (tid < NBLK_SCAN) ? bsums[tid] : 0;
    s[tid] = v;
    __syncthreads();
#pragma unroll
    for (int o = 1; o < 256; o <<= 1) {
        int u = (tid >= o) ? s[tid - o] : 0;
        __syncthreads();
        s[tid] += u;
        __syncthreads();
    }
    if (tid < NBLK_SCAN) bsums[tid] = s[tid] - v;   // exclusive
}

__global__ __launch_bounds__(256) void scan_final(const int* __restrict__ bsums,
                                                  int* __restrict__ deg_cursor,
                                                  int* __restrict__ rs) {
    __shared__ int s[256];
    int tid = threadIdx.x;
    int idx = blockIdx.x * 256 + tid;
    int v = (idx < N_NODES) ? deg_cursor[idx] : 0;
    s[tid] = v;
    __syncthreads();
#pragma unroll
    for (int o = 1; o < 256; o <<= 1) {
        int u = (tid >= o) ? s[tid - o] : 0;
        __syncthreads();
        s[tid] += u;
        __syncthreads();
    }
    int excl = s[tid] - v + bsums[blockIdx.x];
    if (idx < N_NODES) {
        rs[idx] = excl;
        deg_cursor[idx] = excl;
    }
    if (idx == 0) rs[N_NODES] = N_EDGES;
}

// packed = et*N_NODES + src  -> Ht gather offset is packed*128 (t-planar)
__global__ void fill_csr(const int* __restrict__ ei, const int* __restrict__ et,
                         int* __restrict__ cursor, int* __restrict__ packed) {
    int e = blockIdx.x * 256 + threadIdx.x;
    if (e >= N_EDGES) return;
    int dst = ei[N_EDGES + e];
    int pos = atomicAdd(&cursor[dst], 1);
    packed[pos] = et[e] * N_NODES + ei[e];
}

// ---------------------------------------------------------------------------
// R20 relational transform: NO weight staging. B-fragments streamed straight
// from L2 (W = 1 MB, L2-resident; the 64-KB LDS stage + 2 barriers served
// only 4 waves). LDS reduced to a wave-private 32xTPAD transpose buffer
// (34816 B -> 4 blocks/CU, 16 waves/CU, ZERO barriers).
__global__ __launch_bounds__(256, 4) void gemm_rel(const ushort_t* __restrict__ hhi,
                                                   const ushort_t* __restrict__ hlo,
                                                   const ushort_t* __restrict__ Whi,
                                                   const ushort_t* __restrict__ Wlo,
                                                   ushort_t* __restrict__ Ht) {
    __shared__ __align__(16) ushort_t twb[4][32 * TPAD];   // per-wave, 34816 B
    const int tid = threadIdx.x;
    const int wave = tid >> 6, lane = tid & 63;
    const int q = lane >> 4, li = lane & 15;
    const int t = blockIdx.y;
    const int m_base = blockIdx.x * 128 + wave * 32;

    int r0 = m_base + li;      if (r0 > N_NODES - 1) r0 = N_NODES - 1;
    int r1 = m_base + 16 + li; if (r1 > N_NODES - 1) r1 = N_NODES - 1;
    const ushort_t* A0h = hhi + (size_t)r0 * D + q * 8;
    const ushort_t* A0l = hlo + (size_t)r0 * D + q * 8;
    const ushort_t* A1h = hhi + (size_t)r1 * D + q * 8;
    const ushort_t* A1l = hlo + (size_t)r1 * D + q * 8;

    short8 a0h[4], a0l[4], a1h[4], a1l[4];
#pragma unroll
    for (int ks = 0; ks < 4; ++ks) {
        a0h[ks] = *(const short8*)(A0h + ks * 32);
        a0l[ks] = *(const short8*)(A0l + ks * 32);
        a1h[ks] = *(const short8*)(A1h + ks * 32);
        a1l[ks] = *(const short8*)(A1l + ks * 32);
    }

    float4v acc[2][8];
#pragma unroll
    for (int m = 0; m < 2; ++m)
#pragma unroll
        for (int ft = 0; ft < 8; ++ft) acc[m][ft] = (float4v){0.f, 0.f, 0.f, 0.f};

    const ushort_t* Wth = Whi + ((size_t)t << 14);
    const ushort_t* Wtl = Wlo + ((size_t)t << 14);
#pragma unroll
    for (int ks = 0; ks < 4; ++ks) {
#pragma unroll
        for (int ft = 0; ft < 8; ++ft) {
            const int wo = (ft * 16 + li) * 128 + ks * 32 + q * 8;
            short8 bh = *(const short8*)(Wth + wo);
            short8 bl = *(const short8*)(Wtl + wo);
            acc[0][ft] = __builtin_amdgcn_mfma_f32_16x16x32_bf16(a0h[ks], bh, acc[0][ft], 0, 0, 0);
            acc[0][ft] = __builtin_amdgcn_mfma_f32_16x16x32_bf16(a0l[ks], bh, acc[0][ft], 0, 0, 0);
            acc[0][ft] = __builtin_amdgcn_mfma_f32_16x16x32_bf16(a0h[ks], bl, acc[0][ft], 0, 0, 0);
            acc[1][ft] = __builtin_amdgcn_mfma_f32_16x16x32_bf16(a1h[ks], bh, acc[1][ft], 0, 0, 0);
            acc[1][ft] = __builtin_amdgcn_mfma_f32_16x16x32_bf16(a1l[ks], bh, acc[1][ft], 0, 0, 0);
            acc[1][ft] = __builtin_amdgcn_mfma_f32_16x16x32_bf16(a1h[ks], bl, acc[1][ft], 0, 0, 0);
        }
    }

    // wave-private transpose -> contiguous 256 B row stores (t-planar plane)
    ushort_t* tw = &twb[wave][0];
#pragma unroll
    for (int m = 0; m < 2; ++m)
#pragma unroll
        for (int ft = 0; ft < 8; ++ft)
#pragma unroll
            for (int r = 0; r < 4; ++r) {
                __half hv = __float2half_rn(acc[m][ft][r]);
                tw[(m * 16 + q * 4 + r) * TPAD + ft * 16 + li] = __half_as_ushort(hv);
            }
    // wave-local LDS round-trip: compiler's lgkmcnt ordering suffices
#pragma unroll
    for (int i = 0; i < 8; ++i) {
        int row = i * 4 + q;       // 0..31
        int col = li * 8;
        short8 v = *(const short8*)(tw + row * TPAD + col);
        int orow = m_base + row;
        if (orow < N_NODES)
            *(short8*)(Ht + (size_t)t * HT_PLANE + (size_t)orow * D + col) = v;
    }
}

// ---------------------------------------------------------------------------
// CSR aggregation (R11/R19 verbatim): ~50K waves of TLP hide gather latency.
__global__ __launch_bounds__(256) void aggregate_csr(const int* __restrict__ rs,
                                                     const int* __restrict__ packed,
                                                     const ushort_t* __restrict__ Ht,
                                                     const int* __restrict__ nt,
                                                     const float* __restrict__ b_node,
                                                     ushort_t* __restrict__ ahi,
                                                     ushort_t* __restrict__ alo) {
    int n = blockIdx.x * 4 + (threadIdx.x >> 6);
    if (n >= N_NODES) return;
    const int lane = threadIdx.x & 63;
    const int beg = rs[n], end = rs[n + 1];
    const __half2* Ht2 = (const __half2*)Ht;

    float2 acc = ((const float2*)(b_node + (size_t)nt[n] * D))[lane];

    int i = beg;
    for (; i + 3 < end; i += 4) {
        int p0 = packed[i], p1 = packed[i + 1], p2 = packed[i + 2], p3 = packed[i + 3];
        float2 f0 = __half22float2(Ht2[(size_t)p0 * 64 + lane]);
        float2 f1 = __half22float2(Ht2[(size_t)p1 * 64 + lane]);
        float2 f2 = __half22float2(Ht2[(size_t)p2 * 64 + lane]);
        float2 f3 = __half22float2(Ht2[(size_t)p3 * 64 + lane]);
        acc.x += (f0.x + f1.x) + (f2.x + f3.x);
        acc.y += (f0.y + f1.y) + (f2.y + f3.y);
    }
    for (; i < end; ++i) {
        int pk = packed[i];
        float2 fv = __half22float2(Ht2[(size_t)pk * 64 + lane]);
        acc.x += fv.x;
        acc.y += fv.y;
    }

    unsigned short h0, l0, h1, l1;
    splitbf(acc.x, h0, l0);
    splitbf(acc.y, h1, l1);
    ((unsigned*)ahi)[(size_t)n * 64 + lane] = (unsigned)h0 | ((unsigned)h1 << 16);
    ((unsigned*)alo)[(size_t)n * 64 + lane] = (unsigned)l0 | ((unsigned)l1 << 16);
}

// ---------------------------------------------------------------------------
// R20 GRU: ZERO LDS, zero barriers. The A-fragment layout (lane li <- node
// m*16+li, chunk q*8) is directly loadable from global per-lane — the LDS
// staging + 2 barriers of R10-R19 were structural inheritance, and they
// capped residency at 8 waves/CU (the invariant ~67 us across 6 variants).
// W streamed inline from L2 (R15 phase-A pattern, VGPR=64 there);
// launch_bounds(256,4) caps VGPR at 128 -> 16 waves/CU, 2x all priors.
// Swapped-operand MFMA + lane-local epilogue = R13's verified layout.
// Block = 256 thr = 4 waves; grid (1563, 2): blockIdx.y = f-half.
__global__ __launch_bounds__(256, 4) void gru_direct(
    const ushort_t* __restrict__ ahi, const ushort_t* __restrict__ alo,
    const ushort_t* __restrict__ hhi_in, const ushort_t* __restrict__ hlo_in,
    ushort_t* __restrict__ hhi_out, ushort_t* __restrict__ hlo_out,
    const ushort_t* __restrict__ Wihi, const ushort_t* __restrict__ Wilo,
    const ushort_t* __restrict__ Whhi, const ushort_t* __restrict__ Whlo,
    const float* __restrict__ b_ih, const float* __restrict__ b_hh,
    float* __restrict__ h, int write_h)
{
    const int tid = threadIdx.x;
    const int w = tid >> 6, lane = tid & 63;
    const int q = lane >> 4, li = lane & 15;
    const int fg = blockIdx.y * 64 + w * 16 + li;     // W row (A operand)
    const int f0 = blockIdx.y * 64 + w * 16 + q * 4;  // output f base (C rows)
    const int n0 = blockIdx.x * 32;

    const size_t oR = (size_t)fg * D + q * 8;
    const size_t oZ = (size_t)(D + fg) * D + q * 8;
    const size_t oN = (size_t)(2 * D + fg) * D + q * 8;

    // biases: per-lane float4 over f0..f0+3 (16B-aligned)
    float4v bR4 = *(const float4v*)(b_ih + f0);
    float4v bZ4 = *(const float4v*)(b_ih + D + f0);
    float4v bIn4 = *(const float4v*)(b_ih + 2 * D + f0);
    {
        float4v t0 = *(const float4v*)(b_hh + f0);
        float4v t1 = *(const float4v*)(b_hh + D + f0);
        bR4 += t0; bZ4 += t1;
    }
    float4v bHn4 = *(const float4v*)(b_hh + 2 * D + f0);

    // x-fragment global addresses (16-lane row groups -> 256 B segments)
    int r0 = n0 + li;      if (r0 > N_NODES - 1) r0 = N_NODES - 1;
    int r1 = n0 + 16 + li; if (r1 > N_NODES - 1) r1 = N_NODES - 1;
    const size_t xo0 = (size_t)r0 * D + q * 8;
    const size_t xo1 = (size_t)r1 * D + q * 8;

    float4v aR[2], aZ[2], aI[2], aH[2];
#pragma unroll
    for (int m = 0; m < 2; ++m) {
        aR[m] = (float4v){0.f, 0.f, 0.f, 0.f};
        aZ[m] = aR[m]; aI[m] = aR[m]; aH[m] = aR[m];
    }

#pragma unroll
    for (int ks = 0; ks < 4; ++ks) {
        const int off = ks * 32;
        short8 x0ah = *(const short8*)(ahi + xo0 + off);
        short8 x0al = *(const short8*)(alo + xo0 + off);
        short8 x0hh = *(const short8*)(hhi_in + xo0 + off);
        short8 x0hl = *(const short8*)(hlo_in + xo0 + off);
        short8 x1ah = *(const short8*)(ahi + xo1 + off);
        short8 x1al = *(const short8*)(alo + xo1 + off);
        short8 x1hh = *(const short8*)(hhi_in + xo1 + off);
        short8 x1hl = *(const short8*)(hlo_in + xo1 + off);
        short8 wIRh = *(const short8*)(Wihi + oR + off);
        short8 wIRl = *(const short8*)(Wilo + oR + off);
        short8 wHRh = *(const short8*)(Whhi + oR + off);
        short8 wHRl = *(const short8*)(Whlo + oR + off);
        short8 wIZh = *(const short8*)(Wihi + oZ + off);
        short8 wIZl = *(const short8*)(Wilo + oZ + off);
        short8 wHZh = *(const short8*)(Whhi + oZ + off);
        short8 wHZl = *(const short8*)(Whlo + oZ + off);
        short8 wINh = *(const short8*)(Wihi + oN + off);
        short8 wINl = *(const short8*)(Wilo + oN + off);
        short8 wHNh = *(const short8*)(Whhi + oN + off);
        short8 wHNl = *(const short8*)(Whlo + oN + off);

        aR[0] = __builtin_amdgcn_mfma_f32_16x16x32_bf16(wIRh, x0ah, aR[0], 0, 0, 0);
        aR[0] = __builtin_amdgcn_mfma_f32_16x16x32_bf16(wIRh, x0al, aR[0], 0, 0, 0);
        aR[0] = __builtin_amdgcn_mfma_f32_16x16x32_bf16(wIRl, x0ah, aR[0], 0, 0, 0);
        aR[0] = __builtin_amdgcn_mfma_f32_16x16x32_bf16(wHRh, x0hh, aR[0], 0, 0, 0);
        aR[0] = __builtin_amdgcn_mfma_f32_16x16x32_bf16(wHRh, x0hl, aR[0], 0, 0, 0);
        aR[0] = __builtin_amdgcn_mfma_f32_16x16x32_bf16(wHRl, x0hh, aR[0], 0, 0, 0);
        aZ[0] = __builtin_amdgcn_mfma_f32_16x16x32_bf16(wIZh, x0ah, aZ[0], 0, 0, 0);
        aZ[0] = __builtin_amdgcn_mfma_f32_16x16x32_bf16(wIZh, x0al, aZ[0], 0, 0, 0);
        aZ[0] = __builtin_amdgcn_mfma_f32_16x16x32_bf16(wIZl, x0ah, aZ[0], 0, 0, 0);
        aZ[0] = __builtin_amdgcn_mfma_f32_16x16x32_bf16(wHZh, x0hh, aZ[0], 0, 0, 0);
        aZ[0] = __builtin_amdgcn_mfma_f32_16x16x32_bf16(wHZh, x0hl, aZ[0], 0, 0, 0);
        aZ[0] = __builtin_amdgcn_mfma_f32_16x16x32_bf16(wHZl, x0hh, aZ[0], 0, 0, 0);
        aI[0] = __builtin_amdgcn_mfma_f32_16x16x32_bf16(wINh, x0ah, aI[0], 0, 0, 0);
        aI[0] = __builtin_amdgcn_mfma_f32_16x16x32_bf16(wINh, x0al, aI[0], 0, 0, 0);
        aI[0] = __builtin_amdgcn_mfma_f32_16x16x32_bf16(wINl, x0ah, aI[0], 0, 0, 0);
        aH[0] = __builtin_amdgcn_mfma_f32_16x16x32_bf16(wHNh, x0hh, aH[0], 0, 0, 0);
        aH[0] = __builtin_amdgcn_mfma_f32_16x16x32_bf16(wHNh, x0hl, aH[0], 0, 0, 0);
        aH[0] = __builtin_amdgcn_mfma_f32_16x16x32_bf16(wHNl, x0hh, aH[0], 0, 0, 0);

        aR[1] = __builtin_amdgcn_mfma_f32_16x16x32_bf16(wIRh, x1ah, aR[1], 0, 0, 0);
        aR[1] = __builtin_amdgcn_mfma_f32_16x16x32_bf16(wIRh, x1al, aR[1], 0, 0, 0);
        aR[1] = __builtin_amdgcn_mfma_f32_16x16x32_bf16(wIRl, x1ah, aR[1], 0, 0, 0);
        aR[1] = __builtin_amdgcn_mfma_f32_16x16x32_bf16(wHRh, x1hh, aR[1], 0, 0, 0);
        aR[1] = __builtin_amdgcn_mfma_f32_16x16x32_bf16(wHRh, x1hl, aR[1], 0, 0, 0);
        aR[1] = __builtin_amdgcn_mfma_f32_16x16x32_bf16(wHRl, x1hh, aR[1], 0, 0, 0);
        aZ[1] = __builtin_amdgcn_mfma_f32_16x16x32_bf16(wIZh, x1ah, aZ[1], 0, 0, 0);
        aZ[1] = __builtin_amdgcn_mfma_f32_16x16x32_bf16(wIZh, x1al, aZ[1], 0, 0, 0);
        aZ[1] = __builtin_amdgcn_mfma_f32_16x16x32_bf16(wIZl, x1ah, aZ[1], 0, 0, 0);
        aZ[1] = __builtin_amdgcn_mfma_f32_16x16x32_bf16(wHZh, x1hh, aZ[1], 0, 0, 0);
        aZ[1] = __builtin_amdgcn_mfma_f32_16x16x32_bf16(wHZh, x1hl, aZ[1], 0, 0, 0);
        aZ[1] = __builtin_amdgcn_mfma_f32_16x16x32_bf16(wHZl, x1hh, aZ[1], 0, 0, 0);
        aI[1] = __builtin_amdgcn_mfma_f32_16x16x32_bf16(wINh, x1ah, aI[1], 0, 0, 0);
        aI[1] = __builtin_amdgcn_mfma_f32_16x16x32_bf16(wINh, x1al, aI[1], 0, 0, 0);
        aI[1] = __builtin_amdgcn_mfma_f32_16x16x32_bf16(wINl, x1ah, aI[1], 0, 0, 0);
        aH[1] = __builtin_amdgcn_mfma_f32_16x16x32_bf16(wHNh, x1hh, aH[1], 0, 0, 0);
        aH[1] = __builtin_amdgcn_mfma_f32_16x16x32_bf16(wHNh, x1hl, aH[1], 0, 0, 0);
        aH[1] = __builtin_amdgcn_mfma_f32_16x16x32_bf16(wHNl, x1hh, aH[1], 0, 0, 0);
    }

    // ---- epilogue: lane-local (node, f0..f0+3) -> direct stores (R13) ----
#pragma unroll
    for (int m = 0; m < 2; ++m) {
        const int node = n0 + m * 16 + li;
        if (node < N_NODES) {
            const size_t go = (size_t)node * D + f0;
            ushort4v hh4 = *(const ushort4v*)(hhi_in + go);
            ushort4v hl4 = *(const ushort4v*)(hlo_in + go);
            ushort4v sh4, sl4;
            float4v hn4;
#pragma unroll
            for (int r = 0; r < 4; ++r) {
                float hold = bf2f(hh4[r]) + bf2f(hl4[r]);
                float rg = 1.0f / (1.0f + __expf(-(aR[m][r] + bR4[r])));
                float zg = 1.0f / (1.0f + __expf(-(aZ[m][r] + bZ4[r])));
                float narg = aI[m][r] + bIn4[r] + rg * (aH[m][r] + bHn4[r]);
                float ex = __expf(2.0f * narg);
                float ng = 1.0f - 2.0f / (ex + 1.0f);   // tanh
                float hn = (1.0f - zg) * ng + zg * hold;
                hn4[r] = hn;
                unsigned short sh, sl;
                splitbf(hn, sh, sl);
                sh4[r] = sh;
                sl4[r] = sl;
            }
            *(ushort4v*)(hhi_out + go) = sh4;
            *(ushort4v*)(hlo_out + go) = sl4;
            if (write_h) *(float4v*)(h + go) = hn4;
        }
    }
}

// ---------------------------------------------------------------------------
extern "C" void kernel_launch(void* const* d_in, const int* in_sizes, int n_in,
                              void* d_out, int out_size, void* d_ws, size_t ws_size,
                              hipStream_t stream) {
    const int* x      = (const int*)d_in[0];
    const int* ei     = (const int*)d_in[1];
    const int* et     = (const int*)d_in[2];
    const int* nt     = (const int*)d_in[3];
    const float* emb  = (const float*)d_in[4];
    const float* Wrel = (const float*)d_in[5];
    const float* b_node = (const float*)d_in[6];
    const float* W_ih = (const float*)d_in[7];
    const float* W_hh = (const float*)d_in[8];
    const float* b_ih = (const float*)d_in[9];
    const float* b_hh = (const float*)d_in[10];

    float* h = (float*)d_out;
    float* ws = (float*)d_ws;

    // workspace layout (~184 MB, under proven >=234 MB)
    ushort_t* Ht = (ushort_t*)ws;                          // 51,200,000 us (fp16, t-planar)
    ushort_t* us = (ushort_t*)(ws + 25600000);
    ushort_t* ahi  = us;                                   // 6,400,000 each
    ushort_t* alo  = us + 6400000;
    ushort_t* hhi  = us + 12800000;
    ushort_t* hlo  = us + 19200000;
    ushort_t* Whi  = us + 25600000;                        //   131,072 each
    ushort_t* Wlo  = Whi + 131072;
    ushort_t* Wihi = Wlo + 131072;                         //    49,152 each
    ushort_t* Wilo = Wihi + 49152;
    ushort_t* Whhi = Wilo + 49152;
    ushort_t* Whlo = Whhi + 49152;
    int* rs     = (int*)(ws + 38629376);                   //    50,004
    int* packed = rs + 50004;                              //   800,000
    int* bsums  = packed + 800000;                         //       256
    ushort_t* hhi2 = (ushort_t*)(ws + 39479808);           // 6,400,000 each (ping-pong)
    ushort_t* hlo2 = hhi2 + 6400000;
    int* deg    = (int*)ws;                                // transient alias in Ht region (pre-loop only)

    convert_wrelT<<<512, 256, 0, stream>>>(Wrel, Whi, Wlo);
    convert_w<<<192, 256, 0, stream>>>(W_ih, Wihi, Wilo, 3 * D * D);
    convert_w<<<192, 256, 0, stream>>>(W_hh, Whhi, Whlo, 3 * D * D);
    embed_gather<<<N_NODES, 128, 0, stream>>>(x, emb, hhi, hlo);

    hipMemsetAsync(deg, 0, 50000 * sizeof(int), stream);
    count_deg<<<3125, 256, 0, stream>>>(ei, deg);
    scan_blocks<<<NBLK_SCAN, 256, 0, stream>>>(deg, bsums);
    scan_tops<<<1, 256, 0, stream>>>(bsums);
    scan_final<<<NBLK_SCAN, 256, 0, stream>>>(bsums, deg, rs);   // cursor aliases deg
    fill_csr<<<3125, 256, 0, stream>>>(ei, et, deg, packed);

    for (int it = 0; it < 5; ++it) {
        const ushort_t* hi_in = (it & 1) ? hhi2 : hhi;
        const ushort_t* lo_in = (it & 1) ? hlo2 : hlo;
        ushort_t* hi_out = (it & 1) ? hhi : hhi2;
        ushort_t* lo_out = (it & 1) ? hlo : hlo2;
        dim3 g(391, T_TYPES);   // 391*128 = 50048 rows
        gemm_rel<<<g, 256, 0, stream>>>(hi_in, lo_in, Whi, Wlo, Ht);
        aggregate_csr<<<12500, 256, 0, stream>>>(rs, packed, Ht, nt, b_node, ahi, alo);
        dim3 gg(TILES, 2);
        gru_direct<<<gg, 256, 0, stream>>>(ahi, alo, hi_in, lo_in, hi_out, lo_out,
                                           Wihi, Wilo, Whhi, Whlo, b_ih, b_hh,
                                           h, it == 4 ? 1 : 0);
    }
}